// Round 10
// baseline (1187.449 us; speedup 1.0000x reference)
//
#include <hip/hip_runtime.h>

// LDS: sh_x 64 rows x 1024B + per-head-j slots {khT 8K, qhT->w 8K, V 8K}.
#define SM_X     65536
#define SM_SLOT  24576
#define SM_TOTAL 163840                 // exactly 160 KiB (R8 precedent: OK)

typedef __attribute__((ext_vector_type(4))) float f32x4;
typedef __attribute__((ext_vector_type(8))) short bf16x8;
typedef __attribute__((ext_vector_type(4))) short s16x4;

__device__ __forceinline__ short f2b(float f) {
  union { float f; unsigned u; } v; v.f = f;
  return (short)((v.u + 0x7fffu + ((v.u >> 16) & 1u)) >> 16);   // RNE
}
__device__ __forceinline__ float b2f(short u) {
  union { unsigned u; float f; } v; v.u = ((unsigned)(unsigned short)u) << 16;
  return v.f;
}
__device__ __forceinline__ f32x4 mfma16(bf16x8 a, bf16x8 b, f32x4 c) {
  return __builtin_amdgcn_mfma_f32_16x16x32_bf16(a, b, c, 0, 0, 0);
}
// 8KB head-slot swizzle (64 rows x 128B).
__device__ __forceinline__ void* ksw(void* base, int row, int boff) {
  return (char*)base + (row << 7) + (boff ^ ((row & 7) << 4));
}

// xw[b][nr][nc][p] bf16, p = h*64+d (ch = 8d+h); each 1KB row XOR-swizzled by
// ((nr^nc)&7)<<4 -> per-WG lane constant ((l16^rc)&7)<<4.
// PASS=0 (col attn): WG (b, rc=nr), local row n = nc (contiguous 64KB slab)
// PASS=1 (row attn): WG (b, rc=nc), local row n = nr (rows strided 64KB)
// FINAL: epilogue writes standard fp32 out[b][ch][nr][nc] instead of xw.
template <int PASS, int FINAL>
__global__ __launch_bounds__(1024, 4)
void attn_pass(unsigned short* __restrict__ xw, float* __restrict__ outp,
               const short* __restrict__ Wk, const short* __restrict__ Wq,
               const short* __restrict__ Wv,
               const float* __restrict__ bk, const float* __restrict__ bq,
               const float* __restrict__ bv,
               const float* __restrict__ masks)
{
  extern __shared__ char smem[];

  int bid = blockIdx.x;
  if (PASS == 1) bid = (bid & 7) * 64 + (bid >> 3);   // XCD-chunked (R6 mapping)
  const int b  = bid >> 6;
  const int rc = bid & 63;

  const int t    = threadIdx.x;
  const int wv   = t >> 6;
  const int lane = t & 63;
  const int l16  = lane & 15;
  const int g4   = lane >> 4;

  const int sxl  = ((l16 ^ rc) & 7) << 4;   // sh_x/xw swizzle const for this lane
  const int sx30 = sxl & 0x30;
  const int sx64 = sxl & 0x40;

  // PhA: 48 fragment-tasks (proj 3 x head 4 x fi 4), 3 per wave.
  int pj_[3], jj_[3], fi_[3];
  const short* wp0[3];
  const float* bb0[3];
#pragma unroll
  for (int i = 0; i < 3; ++i) {
    const int tid = 3 * wv + i;
    const int proj = tid >> 4, j = (tid >> 2) & 3, fi = tid & 3;
    pj_[i] = proj; jj_[i] = j; fi_[i] = fi;
    const short* W = (proj == 0) ? Wk : (proj == 1) ? Wq : Wv;
    wp0[i] = W + j * 32768 + (fi >> 1) * 16384 + (fi & 1) * 512 + lane * 8;
    bb0[i] = ((proj == 0) ? bk : (proj == 1) ? bq : bv) + j * 64 + fi * 16 + 4 * g4;
  }
  // PhB / PhC wave roles
  const int p2_j = wv >> 2, p2_qb = (wv & 3) * 16;
  const int p34_j = wv & 3, p34_qr = wv >> 2;

  // Depth-2 prefetch of g2=0 A-frags (in flight across the staging barrier)
  bf16x8 pf0[3], pf1[3];
#pragma unroll
  for (int i = 0; i < 3; ++i) {
    pf0[i] = *(const bf16x8*)(wp0[i]);
    pf1[i] = *(const bf16x8*)(wp0[i] + 1024);
  }

  // ---- Stage: straight 16B copy (data pre-swizzled + pre-converted) ----
  {
    const char* xb = (const char*)xw;
    const char* srcb = (PASS == 0)
        ? xb + (size_t)((b * 64 + rc) * 64) * 1024
        : xb + (size_t)(b * 4096 + rc) * 1024;
#pragma unroll
    for (int it = 0; it < 4; ++it) {
      const int idx = it * 1024 + t;
      const int n = idx >> 6, c = idx & 63;
      const char* g = (PASS == 0) ? srcb + n * 1024 + c * 16
                                  : srcb + (size_t)n * 65536 + c * 16;
      *(bf16x8*)(smem + n * 1024 + c * 16) = *(const bf16x8*)g;
    }
  }
  __syncthreads();

  // Per-thread sh_x fragment base (row l16 + g4 k-offset, swizzle folded)
  const char* xfb = smem + l16 * 1024 + ((16 * g4) ^ sx30);

  f32x4 accA[4], accB[4];   // retained O accumulators (heads j, j+4)

#pragma unroll 1
  for (int g2 = 0; g2 < 2; ++g2) {
    // ---- PhA: ALL K/Q/V projections; 16 waves x 3 16-row frag tasks ----
    {
      const short* wpg[3];
#pragma unroll
      for (int i = 0; i < 3; ++i) wpg[i] = wp0[i] + g2 * 131072;
      f32x4 acc[3][4] = {};
      bf16x8 c0[3], c1[3];
#pragma unroll
      for (int i = 0; i < 3; ++i) { c0[i] = pf0[i]; c1[i] = pf1[i]; }
#pragma unroll
      for (int kk = 0; kk < 16; ++kk) {
        bf16x8 nx[3];
#pragma unroll
        for (int i = 0; i < 3; ++i)
          nx[i] = (kk < 14) ? *(const bf16x8*)(wpg[i] + (kk + 2) * 1024) : c1[i];
        const int off = (kk * 64) ^ sx64;
        bf16x8 bbf[4];
#pragma unroll
        for (int nf = 0; nf < 4; ++nf)
          bbf[nf] = *(const bf16x8*)(xfb + nf * 16384 + off);
#pragma unroll
        for (int i = 0; i < 3; ++i)
#pragma unroll
          for (int nf = 0; nf < 4; ++nf)
            acc[i][nf] = mfma16(c0[i], bbf[nf], acc[i][nf]);
#pragma unroll
        for (int i = 0; i < 3; ++i) { c0[i] = c1[i]; c1[i] = nx[i]; }
      }
#pragma unroll
      for (int i = 0; i < 3; ++i) {
        const float4 bs = *(const float4*)(bb0[i] + g2 * 256);   // h += 4
        const float ba[4] = { bs.x, bs.y, bs.z, bs.w };
        if (pj_[i] < 2) {            // K/Q: transposed s16x4 store [n][d]
          short* ob = (short*)(smem + SM_X + jj_[i] * SM_SLOT + pj_[i] * 8192);
#pragma unroll
          for (int nf = 0; nf < 4; ++nf) {
            s16x4 pk;
#pragma unroll
            for (int r = 0; r < 4; ++r) pk[r] = f2b(acc[i][nf][r] + ba[r]);
            *(s16x4*)ksw(ob, nf * 16 + l16, 2 * (fi_[i] * 16 + 4 * g4)) = pk;
          }
        } else {                     // V: normal [d][key], scalar stores
          short* vb_ = (short*)(smem + SM_X + jj_[i] * SM_SLOT + 16384);
#pragma unroll
          for (int nf = 0; nf < 4; ++nf)
#pragma unroll
            for (int r = 0; r < 4; ++r)
              *(short*)ksw(vb_, fi_[i] * 16 + 4 * g4 + r, 2 * (nf * 16 + l16)) =
                  f2b(acc[i][nf][r] + ba[r]);
        }
      }
    }
    __syncthreads();

    // ---- PhB: S^T = Q.K^T + softmax over keys; w overlays qslot rows ----
    {
      char* gb = smem + SM_X + p2_j * SM_SLOT;
      short* kb  = (short*)gb;
      short* qb_ = (short*)(gb + 8192);
      float pen[4];
#pragma unroll
      for (int tt = 0; tt < 4; ++tt) {
        const int key = tt * 16 + l16;
        const float m = (PASS == 0) ? masks[b * 4096 + rc * 64 + key]
                                    : masks[b * 4096 + key * 64 + rc];
        pen[tt] = (1.0f - m) * 1e8f;
      }
      f32x4 st[4] = {};
#pragma unroll
      for (int dk = 0; dk < 2; ++dk) {
        const int bo = dk * 64 + 16 * g4;
        bf16x8 a = *(const bf16x8*)ksw(qb_, p2_qb + l16, bo);
#pragma unroll
        for (int tt = 0; tt < 4; ++tt) {
          bf16x8 bbf = *(const bf16x8*)ksw(kb, tt * 16 + l16, bo);
          st[tt] = mfma16(a, bbf, st[tt]);   // S[q=qb+4g4+r][key=16tt+l16]
        }
      }
      const float scale = 0.044194173824159216f;   // 1/sqrt(512)
      float v[4][4], mx[4], sm[4];
#pragma unroll
      for (int tt = 0; tt < 4; ++tt)
#pragma unroll
        for (int r = 0; r < 4; ++r) v[tt][r] = st[tt][r] * scale - pen[tt];
#pragma unroll
      for (int r = 0; r < 4; ++r)
        mx[r] = fmaxf(fmaxf(v[0][r], v[1][r]), fmaxf(v[2][r], v[3][r]));
#pragma unroll
      for (int d = 1; d <= 8; d <<= 1)
#pragma unroll
        for (int r = 0; r < 4; ++r) mx[r] = fmaxf(mx[r], __shfl_xor(mx[r], d));
#pragma unroll
      for (int r = 0; r < 4; ++r) sm[r] = 0.f;
#pragma unroll
      for (int tt = 0; tt < 4; ++tt)
#pragma unroll
        for (int r = 0; r < 4; ++r) { v[tt][r] = __expf(v[tt][r] - mx[r]); sm[r] += v[tt][r]; }
#pragma unroll
      for (int d = 1; d <= 8; d <<= 1)
#pragma unroll
        for (int r = 0; r < 4; ++r) sm[r] += __shfl_xor(sm[r], d);
#pragma unroll
      for (int r = 0; r < 4; ++r) sm[r] = 1.0f / sm[r];
#pragma unroll
      for (int tt = 0; tt < 4; ++tt)
#pragma unroll
        for (int r = 0; r < 4; ++r)
          *(short*)ksw(qb_, p2_qb + 4 * g4 + r, 2 * (tt * 16 + l16)) =
              f2b(v[tt][r] * sm[r]);   // w[q][key]
    }
    __syncthreads();

    // ---- PhC: O[d][q] = sum_key V[d][key]*w[q][key] -> retained registers ----
    {
      char* gb = smem + SM_X + p34_j * SM_SLOT;
      short* wbuf = (short*)(gb + 8192);
      short* vbuf = (short*)(gb + 16384);
      f32x4 po[4] = {};
#pragma unroll
      for (int dk = 0; dk < 2; ++dk) {
        const int bo = dk * 64 + 16 * g4;
        bf16x8 bw = *(const bf16x8*)ksw(wbuf, p34_qr * 16 + l16, bo);  // w rows q
#pragma unroll
        for (int nf = 0; nf < 4; ++nf) {
          bf16x8 av = *(const bf16x8*)ksw(vbuf, nf * 16 + l16, bo);    // V rows d
          po[nf] = mfma16(av, bw, po[nf]);   // po[nf][r]=O[d=nf*16+4g4+r][q]
        }
      }
      if (g2 == 0) {
        accA[0] = po[0]; accA[1] = po[1]; accA[2] = po[2]; accA[3] = po[3];
        // depth-2 prefetch of g2=1 A-frags (drained by the barrier below)
#pragma unroll
        for (int i = 0; i < 3; ++i) {
          pf0[i] = *(const bf16x8*)(wp0[i] + 131072);
          pf1[i] = *(const bf16x8*)(wp0[i] + 131072 + 1024);
        }
      } else {
        accB[0] = po[0]; accB[1] = po[1]; accB[2] = po[2]; accB[3] = po[3];
      }
    }
    if (g2 == 0) __syncthreads();   // protect slots before g2=1 PhA overwrites
  }

  // ---- Epilogue: residual from sh_x; write xw (bf16 swz) or fp32 out ----
  {
    const int q = p34_qr * 16 + l16;
    const char* lrow = smem + q * 1024;
    const size_t rowg = (PASS == 0) ? (size_t)((b * 64 + rc) * 64 + q)
                                    : (size_t)((b * 64 + q) * 64 + rc);
    char* grow = (char*)xw + rowg * 1024;
#pragma unroll
    for (int hh = 0; hh < 2; ++hh) {
      const int h = hh * 4 + p34_j;
#pragma unroll
      for (int nf = 0; nf < 4; ++nf) {
        const int cb = (h * 128 + nf * 32 + 8 * g4) ^ sxl;
        const s16x4 rx = *(const s16x4*)(lrow + cb);
        const f32x4 av = hh ? accB[nf] : accA[nf];
        if (FINAL) {
#pragma unroll
          for (int r = 0; r < 4; ++r) {
            const int ch = 8 * (nf * 16 + 4 * g4 + r) + h;
            const size_t off = (size_t)b * 2097152 + (size_t)ch * 4096
                             + ((PASS == 0) ? rc * 64 + q : q * 64 + rc);
            outp[off] = av[r] + b2f(rx[r]);
          }
        } else {
          s16x4 ov;
#pragma unroll
          for (int r = 0; r < 4; ++r) ov[r] = f2b(av[r] + b2f(rx[r]));
          *(s16x4*)(grow + cb) = ov;
        }
      }
    }
  }
}

// x[b][ch][nr][nc] f32 -> xw[b][nr][nc][p] bf16 pre-swizzled.
__global__ __launch_bounds__(256)
void prep_x(const float* __restrict__ x, unsigned short* __restrict__ xw)
{
  extern __shared__ float tile[];            // [64][521]
  const int b = blockIdx.x >> 6, nr = blockIdx.x & 63;
  const float* src = x + (size_t)b * 2097152 + nr * 64;
  const int t = threadIdx.x;
#pragma unroll 4
  for (int it = 0; it < 32; ++it) {
    const int idx = it * 256 + t;
    const int ch = idx >> 4, nc4 = (idx & 15) * 4;
    const float4 v = *(const float4*)(src + (size_t)ch * 4096 + nc4);
    const int p = ((ch & 7) << 6) | (ch >> 3);
    const int pp = p + (p >> 6);
    tile[(nc4 + 0) * 521 + pp] = v.x;
    tile[(nc4 + 1) * 521 + pp] = v.y;
    tile[(nc4 + 2) * 521 + pp] = v.z;
    tile[(nc4 + 3) * 521 + pp] = v.w;
  }
  __syncthreads();
  unsigned short* dst = xw + (size_t)(b * 64 + nr) * 32768;
#pragma unroll 4
  for (int it = 0; it < 16; ++it) {
    const int idx = it * 256 + t;
    const int nc = idx >> 6, p8 = (idx & 63) * 8;
    bf16x8 o;
#pragma unroll
    for (int j = 0; j < 8; ++j) {
      const int p = p8 + j;
      o[j] = f2b(tile[nc * 521 + p + (p >> 6)]);
    }
    const int sx = ((nr ^ nc) & 7) << 4;
    *(bf16x8*)((char*)(dst + nc * 512) + ((2 * p8) ^ sx)) = o;
  }
}

// Un-permute one b-slab: tmp[nr][nc][p] bf16 swz -> out[ch][nr][nc] f32
__global__ __launch_bounds__(256)
void unperm_b(const unsigned short* __restrict__ tmp, float* __restrict__ out)
{
  __shared__ float tile[64 * 65];
  const int nr = blockIdx.x >> 3, pb = blockIdx.x & 7;
  const int t = threadIdx.x;
#pragma unroll
  for (int it = 0; it < 4; ++it) {
    const int idx = it * 256 + t;
    const int nc = idx >> 4, p4 = (idx & 15) * 4;
    const int sx = ((nr ^ nc) & 7) << 4;
    const s16x4 v = *(const s16x4*)((const char*)(tmp + ((size_t)nr * 64 + nc) * 512)
                                    + ((2 * (pb * 64 + p4)) ^ sx));
#pragma unroll
    for (int j = 0; j < 4; ++j) tile[nc * 65 + p4 + j] = b2f(v[j]);
  }
  __syncthreads();
#pragma unroll
  for (int it = 0; it < 4; ++it) {
    const int idx = it * 256 + t;
    const int pi = idx >> 4, nc4 = (idx & 15) * 4;
    const int ch = 8 * pi + pb;
    float4 o;
#pragma unroll
    for (int j = 0; j < 4; ++j) (&o.x)[j] = tile[(nc4 + j) * 65 + pi];
    *(float4*)(out + (size_t)ch * 4096 + nr * 64 + nc4) = o;
  }
}

// Weights [3][512][512] f32 -> fragment order with k-elements in p-order.
__global__ void pack_w(const float* __restrict__ w0, const float* __restrict__ w1,
                       const float* __restrict__ w2, const float* __restrict__ w3,
                       const float* __restrict__ w4, const float* __restrict__ w5,
                       short* __restrict__ dst)
{
  const float* s;
  switch (blockIdx.y) {
    case 0: s = w0; break; case 1: s = w1; break; case 2: s = w2; break;
    case 3: s = w3; break; case 4: s = w4; break; default: s = w5; break;
  }
  const int idx = blockIdx.x * 256 + threadIdx.x;   // 0 .. 196607
  const int l = idx >> 16;
  const int r = idx & 65535;
  const int o = r >> 7, c4 = (r & 127) * 4;
  const float4 v = *(const float4*)(s + ((size_t)l * 512 + o) * 512 + c4);
  const int h = o & 7, row8 = o >> 3;
  const int mh = row8 >> 5, f = (row8 >> 4) & 1, l16r = row8 & 15;
  short* db = dst + (size_t)blockIdx.y * 786432 + (size_t)l * 262144;
#pragma unroll
  for (int j = 0; j < 4; ++j) {
    const int ch = c4 + j;
    const int p = ((ch & 7) << 6) | (ch >> 3);
    const int jj = p & 7, g4p = (p >> 3) & 3, kk = p >> 5;
    const int lane = g4p * 16 + l16r;
    db[(size_t)(((((h * 2 + mh) * 16 + kk) * 2 + f) * 64 + lane)) * 8 + jj] =
        f2b((&v.x)[j]);
  }
}

// Biases [3][512] f32 -> [name][l][h][64] f32
__global__ void pack_b(const float* __restrict__ b0, const float* __restrict__ b1,
                       const float* __restrict__ b2, const float* __restrict__ b3,
                       const float* __restrict__ b4, const float* __restrict__ b5,
                       float* __restrict__ dst)
{
  const int idx = blockIdx.x * 256 + threadIdx.x;   // 0..9215
  const int name = idx / 1536;
  const int rem  = idx - name * 1536;
  const int l = rem >> 9;
  const int p = rem & 511;
  const int h = p >> 6, d = p & 63;
  const float* s;
  switch (name) {
    case 0: s = b0; break; case 1: s = b1; break; case 2: s = b2; break;
    case 3: s = b3; break; case 4: s = b4; break; default: s = b5; break;
  }
  dst[idx] = s[l * 512 + 8 * d + h];
}

__global__ void copy_masks(const float* __restrict__ m, float* __restrict__ o) {
  const int i = blockIdx.x * 256 + threadIdx.x;
  ((float4*)o)[i] = ((const float4*)m)[i];
}

extern "C" void kernel_launch(void* const* d_in, const int* in_sizes, int n_in,
                              void* d_out, int out_size, void* d_ws, size_t ws_size,
                              hipStream_t stream)
{
  const float* x0    = (const float*)d_in[0];
  const float* masks = (const float*)d_in[1];
  short* wbf  = (short*)d_ws;                        // packed weights, 9.44 MB
  float* bws  = (float*)((char*)d_ws + 9437184);     // packed biases
  float* xbuf = (float*)d_out;
  float* mout = xbuf + 16777216;

  const size_t xw_off = 9474048;                     // after weights + biases
  const bool big = ws_size >= xw_off + (size_t)33554432;   // xw bf16 = 32 MB
  unsigned short* xw = big ? (unsigned short*)((char*)d_ws + xw_off)
                           : (unsigned short*)d_out;

  pack_w<<<dim3(768, 6), 256, 0, stream>>>(
      (const float*)d_in[2], (const float*)d_in[3], (const float*)d_in[4],
      (const float*)d_in[5], (const float*)d_in[6], (const float*)d_in[7], wbf);
  pack_b<<<36, 256, 0, stream>>>(
      (const float*)d_in[8], (const float*)d_in[9], (const float*)d_in[10],
      (const float*)d_in[11], (const float*)d_in[12], (const float*)d_in[13], bws);
  prep_x<<<512, 256, 64 * 521 * 4, stream>>>(x0, xw);
  copy_masks<<<32, 256, 0, stream>>>(masks, mout);

  const size_t WPL = 262144;
  for (int l = 0; l < 3; ++l) {
    attn_pass<0, 0><<<512, 1024, SM_TOTAL, stream>>>(
        xw, xbuf,
        wbf + (0 * 3 + l) * WPL, wbf + (1 * 3 + l) * WPL, wbf + (2 * 3 + l) * WPL,
        bws + (0 * 3 + l) * 512, bws + (1 * 3 + l) * 512, bws + (2 * 3 + l) * 512,
        masks);
    const short* rwk = wbf + (3 * 3 + l) * WPL;
    const short* rwq = wbf + (4 * 3 + l) * WPL;
    const short* rwv = wbf + (5 * 3 + l) * WPL;
    const float* rbk = bws + (3 * 3 + l) * 512;
    const float* rbq = bws + (4 * 3 + l) * 512;
    const float* rbv = bws + (5 * 3 + l) * 512;
    if (l == 2 && big)
      attn_pass<1, 1><<<512, 1024, SM_TOTAL, stream>>>(
          xw, xbuf, rwk, rwq, rwv, rbk, rbq, rbv, masks);
    else
      attn_pass<1, 0><<<512, 1024, SM_TOTAL, stream>>>(
          xw, xbuf, rwk, rwq, rwv, rbk, rbq, rbv, masks);
  }

  if (!big) {
    // xw (bf16, 32MB) aliases the front of d_out; un-permute per b-slab via a
    // ws bounce, in REVERSE order so out-writes never clobber unread slabs.
    for (int b = 7; b >= 0; --b) {
      hipMemcpyAsync(wbf, xw + (size_t)b * 2097152, 4194304,
                     hipMemcpyDeviceToDevice, stream);
      unperm_b<<<512, 256, 0, stream>>>((const unsigned short*)wbf,
                                        xbuf + (size_t)b * 2097152);
    }
  }
}

// Round 11
// 632.681 us; speedup vs baseline: 1.8769x; 1.8769x over previous
//
#include <hip/hip_runtime.h>

// LDS: sh_x 64 rows x 1024B + per-head-j {khT 8K, qhT->w 8K} x4 + V 8K x4.
#define SM_X     65536
#define SM_HD    16384
#define SM_VB    131072                 // V slots base
#define SM_TOTAL 163840                 // exactly 160 KiB (launches: R8 precedent)

typedef __attribute__((ext_vector_type(4))) float f32x4;
typedef __attribute__((ext_vector_type(8))) short bf16x8;
typedef __attribute__((ext_vector_type(4))) short s16x4;

__device__ __forceinline__ short f2b(float f) {
  union { float f; unsigned u; } v; v.f = f;
  return (short)((v.u + 0x7fffu + ((v.u >> 16) & 1u)) >> 16);   // RNE
}
__device__ __forceinline__ float b2f(short u) {
  union { unsigned u; float f; } v; v.u = ((unsigned)(unsigned short)u) << 16;
  return v.f;
}
__device__ __forceinline__ f32x4 mfma16(bf16x8 a, bf16x8 b, f32x4 c) {
  return __builtin_amdgcn_mfma_f32_16x16x32_bf16(a, b, c, 0, 0, 0);
}
// 8KB head-slot swizzle (64 rows x 128B).
__device__ __forceinline__ void* ksw(void* base, int row, int boff) {
  return (char*)base + (row << 7) + (boff ^ ((row & 7) << 4));
}

// xw[b][nr][nc][p] bf16, p = h*64+d (ch = 8d+h); each 1KB row XOR-swizzled by
// ((nr^nc)&7)<<4 -> per-WG lane constant ((l16^rc)&7)<<4.
// PASS=0 (col attn): WG (b, rc=nr), local row n = nc (contiguous 64KB slab)
// PASS=1 (row attn): WG (b, rc=nc), local row n = nr (rows strided 64KB)
// FINAL: epilogue writes standard fp32 out[b][ch][nr][nc] instead of xw.
template <int PASS, int FINAL>
__global__ __launch_bounds__(1024, 4)
void attn_pass(unsigned short* __restrict__ xw, float* __restrict__ outp,
               const short* __restrict__ Wk, const short* __restrict__ Wq,
               const short* __restrict__ Wv,
               const float* __restrict__ bk, const float* __restrict__ bq,
               const float* __restrict__ bv,
               const float* __restrict__ masks)
{
  extern __shared__ char smem[];

  int bid = blockIdx.x;
  if (PASS == 1) bid = (bid & 7) * 64 + (bid >> 3);   // XCD-chunked (R6 mapping)
  const int b  = bid >> 6;
  const int rc = bid & 63;

  const int t    = threadIdx.x;
  const int wv   = t >> 6;
  const int lane = t & 63;
  const int l16  = lane & 15;
  const int g4   = lane >> 4;

  const int sxl  = ((l16 ^ rc) & 7) << 4;   // sh_x/xw swizzle const for this lane
  const int sx30 = sxl & 0x30;
  const int sx64 = sxl & 0x40;

  const int p1_j = wv & 3, p1_proj = (wv >> 2) & 1, p1_mh = wv >> 3;
  const int s_j  = wv >> 1, s_qh = wv & 1;            // S-wave role (wv<8)
  const int v_j  = (wv & 7) >> 1, v_mh = wv & 1;      // V-wave role (wv>=8)
  const int p34_j = wv & 3, p34_qr = wv >> 2;

  const short* wb_nh = (p1_proj ? Wq : Wk) + p1_mh * 16384 + lane * 8;
  const float* bp1   = p1_proj ? bq : bk;
  // Depth-2 K/Q prefetch for g2=0 (in flight across the staging barrier)
  bf16x8 pa0 = *(const bf16x8*)(wb_nh + p1_j * 32768);
  bf16x8 pa1 = *(const bf16x8*)(wb_nh + p1_j * 32768 + 512);
  bf16x8 pa2 = *(const bf16x8*)(wb_nh + p1_j * 32768 + 1024);
  bf16x8 pa3 = *(const bf16x8*)(wb_nh + p1_j * 32768 + 1536);
  bf16x8 pv0, pv1, pv2, pv3;

  // ---- Stage: straight 16B copy (data pre-swizzled + pre-converted) ----
  {
    const char* xb = (const char*)xw;
    const char* srcb = (PASS == 0)
        ? xb + (size_t)((b * 64 + rc) * 64) * 1024
        : xb + (size_t)(b * 4096 + rc) * 1024;
#pragma unroll
    for (int it = 0; it < 4; ++it) {
      const int idx = it * 1024 + t;
      const int n = idx >> 6, c = idx & 63;
      const char* g = (PASS == 0) ? srcb + n * 1024 + c * 16
                                  : srcb + (size_t)n * 65536 + c * 16;
      *(bf16x8*)(smem + n * 1024 + c * 16) = *(const bf16x8*)g;
    }
  }
  __syncthreads();

  // Per-thread sh_x fragment base (row l16 + g4 k-offset, swizzle folded)
  const char* xfb = smem + l16 * 1024 + ((16 * g4) ^ sx30);

#pragma unroll 1
  for (int g2 = 0; g2 < 2; ++g2) {
    // ---- P1: K/Q projections (one (head, proj, half) per wave), depth-2 ----
    {
      const int h = g2 * 4 + p1_j;
      const short* wb = wb_nh + h * 32768;
      char* gb = smem + SM_X + p1_j * SM_HD;
      short* ob = (short*)(gb + (p1_proj ? 8192 : 0));
      f32x4 acc[2][4] = {};
      bf16x8 c0a = pa0, c0b = pa1, c1a = pa2, c1b = pa3;
#pragma unroll
      for (int kk = 0; kk < 16; ++kk) {
        bf16x8 nna = c1a, nnb = c1b;
        if (kk < 14) {
          nna = *(const bf16x8*)(wb + (kk + 2) * 1024);
          nnb = *(const bf16x8*)(wb + (kk + 2) * 1024 + 512);
        }
        const int off = (kk * 64) ^ sx64;
#pragma unroll
        for (int nf = 0; nf < 4; ++nf) {
          bf16x8 bb = *(const bf16x8*)(xfb + nf * 16384 + off);
          acc[0][nf] = mfma16(c0a, bb, acc[0][nf]);
          acc[1][nf] = mfma16(c0b, bb, acc[1][nf]);
        }
        c0a = c1a; c0b = c1b; c1a = nna; c1b = nnb;
      }
      // V prefetch for this g2 (issued before the barrier, used in P2m)
      if (wv >= 8) {
        const short* wbv = Wv + (size_t)(g2 * 4 + v_j) * 32768
                         + v_mh * 16384 + lane * 8;
        pv0 = *(const bf16x8*)(wbv);
        pv1 = *(const bf16x8*)(wbv + 512);
        pv2 = *(const bf16x8*)(wbv + 1024);
        pv3 = *(const bf16x8*)(wbv + 1536);
      }
      const float* bp = bp1 + h * 64;
#pragma unroll
      for (int mi = 0; mi < 2; ++mi) {
        const int db = p1_mh * 32 + mi * 16 + 4 * g4;
        const float4 bs = *(const float4*)(bp + db);
        const float ba[4] = { bs.x, bs.y, bs.z, bs.w };
#pragma unroll
        for (int nf = 0; nf < 4; ++nf) {
          s16x4 pk;
#pragma unroll
          for (int r = 0; r < 4; ++r) pk[r] = f2b(acc[mi][nf][r] + ba[r]);
          *(s16x4*)ksw(ob, nf * 16 + l16, 2 * db) = pk;   // khT/qhT [n][d]
        }
      }
    }
    __syncthreads();

    // ---- P2m: waves 0-7: S + softmax -> w.  waves 8-15: V projection ----
    if (wv < 8) {
      char* gb = smem + SM_X + s_j * SM_HD;
      short* kb  = (short*)gb;
      short* qb_ = (short*)(gb + 8192);
      float pen[4];
#pragma unroll
      for (int tt = 0; tt < 4; ++tt) {
        const int key = tt * 16 + l16;
        const float m = (PASS == 0) ? masks[b * 4096 + rc * 64 + key]
                                    : masks[b * 4096 + key * 64 + rc];
        pen[tt] = (1.0f - m) * 1e8f;
      }
      f32x4 st[2][4] = {};
#pragma unroll
      for (int dk = 0; dk < 2; ++dk) {
        const int bo = dk * 64 + 16 * g4;
        bf16x8 a0 = *(const bf16x8*)ksw(qb_, s_qh * 32 + l16, bo);
        bf16x8 a1 = *(const bf16x8*)ksw(qb_, s_qh * 32 + 16 + l16, bo);
#pragma unroll
        for (int tt = 0; tt < 4; ++tt) {
          bf16x8 bb = *(const bf16x8*)ksw(kb, tt * 16 + l16, bo);
          st[0][tt] = mfma16(a0, bb, st[0][tt]);  // S[qh*32+4g4+r][16tt+l16]
          st[1][tt] = mfma16(a1, bb, st[1][tt]);  // S[qh*32+16+4g4+r][...]
        }
      }
      const float scale = 0.044194173824159216f;   // 1/sqrt(512)
      float v[2][4][4], mx[2][4], sm[2][4];
#pragma unroll
      for (int qi = 0; qi < 2; ++qi) {
#pragma unroll
        for (int tt = 0; tt < 4; ++tt)
#pragma unroll
          for (int r = 0; r < 4; ++r) v[qi][tt][r] = st[qi][tt][r] * scale - pen[tt];
#pragma unroll
        for (int r = 0; r < 4; ++r)
          mx[qi][r] = fmaxf(fmaxf(v[qi][0][r], v[qi][1][r]),
                            fmaxf(v[qi][2][r], v[qi][3][r]));
#pragma unroll
        for (int d = 1; d <= 8; d <<= 1)
#pragma unroll
          for (int r = 0; r < 4; ++r)
            mx[qi][r] = fmaxf(mx[qi][r], __shfl_xor(mx[qi][r], d));
#pragma unroll
        for (int r = 0; r < 4; ++r) sm[qi][r] = 0.f;
#pragma unroll
        for (int tt = 0; tt < 4; ++tt)
#pragma unroll
          for (int r = 0; r < 4; ++r) {
            v[qi][tt][r] = __expf(v[qi][tt][r] - mx[qi][r]);
            sm[qi][r] += v[qi][tt][r];
          }
#pragma unroll
        for (int d = 1; d <= 8; d <<= 1)
#pragma unroll
          for (int r = 0; r < 4; ++r) sm[qi][r] += __shfl_xor(sm[qi][r], d);
#pragma unroll
        for (int r = 0; r < 4; ++r) sm[qi][r] = 1.0f / sm[qi][r];
#pragma unroll
        for (int tt = 0; tt < 4; ++tt)
#pragma unroll
          for (int r = 0; r < 4; ++r)
            *(short*)ksw(qb_, s_qh * 32 + qi * 16 + 4 * g4 + r,
                         2 * (tt * 16 + l16)) =
                f2b(v[qi][tt][r] * sm[qi][r]);   // w[q][key]
      }
    } else {
      const short* wbv = Wv + (size_t)(g2 * 4 + v_j) * 32768
                       + v_mh * 16384 + lane * 8;
      short* vbuf = (short*)(smem + SM_VB + v_j * 8192);
      f32x4 acc[2][4] = {};
      bf16x8 c0a = pv0, c0b = pv1, c1a = pv2, c1b = pv3;
#pragma unroll
      for (int kk = 0; kk < 16; ++kk) {
        bf16x8 nna = c1a, nnb = c1b;
        if (kk < 14) {
          nna = *(const bf16x8*)(wbv + (kk + 2) * 1024);
          nnb = *(const bf16x8*)(wbv + (kk + 2) * 1024 + 512);
        }
        const int off = (kk * 64) ^ sx64;
#pragma unroll
        for (int nf = 0; nf < 4; ++nf) {
          bf16x8 bb = *(const bf16x8*)(xfb + nf * 16384 + off);
          acc[0][nf] = mfma16(c0a, bb, acc[0][nf]);
          acc[1][nf] = mfma16(c0b, bb, acc[1][nf]);
        }
        c0a = c1a; c0b = c1b; c1a = nna; c1b = nnb;
      }
      const float* bp = bv + (g2 * 4 + v_j) * 64;
#pragma unroll
      for (int mi = 0; mi < 2; ++mi) {
        const int db = v_mh * 32 + mi * 16 + 4 * g4;
        const float4 bs = *(const float4*)(bp + db);
        const float ba[4] = { bs.x, bs.y, bs.z, bs.w };
#pragma unroll
        for (int nf = 0; nf < 4; ++nf)
#pragma unroll
          for (int r = 0; r < 4; ++r)
            *(short*)ksw(vbuf, db + r, 2 * (nf * 16 + l16)) =
                f2b(acc[mi][nf][r] + ba[r]);     // V[d][key]
      }
    }
    __syncthreads();

    // ---- P3: O[d][q] = sum_key V[d][key]*w[q][key]; fused scattered epilogue ----
    {
      const int h = g2 * 4 + p34_j;
      short* wbuf = (short*)(smem + SM_X + p34_j * SM_HD + 8192);
      short* vbuf = (short*)(smem + SM_VB + p34_j * 8192);
      f32x4 po[4] = {};
#pragma unroll
      for (int dk = 0; dk < 2; ++dk) {
        const int bo = dk * 64 + 16 * g4;
        bf16x8 bw = *(const bf16x8*)ksw(wbuf, p34_qr * 16 + l16, bo);  // w rows q
#pragma unroll
        for (int nf = 0; nf < 4; ++nf) {
          bf16x8 av = *(const bf16x8*)ksw(vbuf, nf * 16 + l16, bo);    // V rows d
          po[nf] = mfma16(av, bw, po[nf]);   // po[nf][r]=O[d=nf*16+4g4+r][q]
        }
      }
      const int q = p34_qr * 16 + l16;
      const char* lrow = smem + q * 1024;   // residual x row (bf16 swz)
      const size_t rowg = (PASS == 0) ? (size_t)((b * 64 + rc) * 64 + q)
                                      : (size_t)((b * 64 + q) * 64 + rc);
      char* grow = (char*)xw + rowg * 1024;
#pragma unroll
      for (int nf = 0; nf < 4; ++nf) {
        const int cb = (h * 128 + nf * 32 + 8 * g4) ^ sxl;
        const s16x4 rx = *(const s16x4*)(lrow + cb);
        if (FINAL) {
#pragma unroll
          for (int r = 0; r < 4; ++r) {
            const int ch = 8 * (nf * 16 + 4 * g4 + r) + h;
            const size_t off = (size_t)b * 2097152 + (size_t)ch * 4096
                             + ((PASS == 0) ? rc * 64 + q : q * 64 + rc);
            outp[off] = po[nf][r] + b2f(rx[r]);
          }
        } else {
          s16x4 ov;
#pragma unroll
          for (int r = 0; r < 4; ++r) ov[r] = f2b(po[nf][r] + b2f(rx[r]));
          *(s16x4*)(grow + cb) = ov;
        }
      }
      if (g2 == 0) {   // depth-2 prefetch of g2=1 K/Q (drained by barrier)
        const short* wb2 = wb_nh + (4 + p1_j) * 32768;
        pa0 = *(const bf16x8*)(wb2);
        pa1 = *(const bf16x8*)(wb2 + 512);
        pa2 = *(const bf16x8*)(wb2 + 1024);
        pa3 = *(const bf16x8*)(wb2 + 1536);
      }
    }
    if (g2 == 0) __syncthreads();   // protect slots before g2=1 P1 overwrites
  }
}

// x[b][ch][nr][nc] f32 -> xw[b][nr][nc][p] bf16 pre-swizzled.
__global__ __launch_bounds__(256)
void prep_x(const float* __restrict__ x, unsigned short* __restrict__ xw)
{
  extern __shared__ float tile[];            // [64][521]
  const int b = blockIdx.x >> 6, nr = blockIdx.x & 63;
  const float* src = x + (size_t)b * 2097152 + nr * 64;
  const int t = threadIdx.x;
#pragma unroll 4
  for (int it = 0; it < 32; ++it) {
    const int idx = it * 256 + t;
    const int ch = idx >> 4, nc4 = (idx & 15) * 4;
    const float4 v = *(const float4*)(src + (size_t)ch * 4096 + nc4);
    const int p = ((ch & 7) << 6) | (ch >> 3);
    const int pp = p + (p >> 6);
    tile[(nc4 + 0) * 521 + pp] = v.x;
    tile[(nc4 + 1) * 521 + pp] = v.y;
    tile[(nc4 + 2) * 521 + pp] = v.z;
    tile[(nc4 + 3) * 521 + pp] = v.w;
  }
  __syncthreads();
  unsigned short* dst = xw + (size_t)(b * 64 + nr) * 32768;
#pragma unroll 4
  for (int it = 0; it < 16; ++it) {
    const int idx = it * 256 + t;
    const int nc = idx >> 6, p8 = (idx & 63) * 8;
    bf16x8 o;
#pragma unroll
    for (int j = 0; j < 8; ++j) {
      const int p = p8 + j;
      o[j] = f2b(tile[nc * 521 + p + (p >> 6)]);
    }
    const int sx = ((nr ^ nc) & 7) << 4;
    *(bf16x8*)((char*)(dst + nc * 512) + ((2 * p8) ^ sx)) = o;
  }
}

// Un-permute one b-slab: tmp[nr][nc][p] bf16 swz -> out[ch][nr][nc] f32
__global__ __launch_bounds__(256)
void unperm_b(const unsigned short* __restrict__ tmp, float* __restrict__ out)
{
  __shared__ float tile[64 * 65];
  const int nr = blockIdx.x >> 3, pb = blockIdx.x & 7;
  const int t = threadIdx.x;
#pragma unroll
  for (int it = 0; it < 4; ++it) {
    const int idx = it * 256 + t;
    const int nc = idx >> 4, p4 = (idx & 15) * 4;
    const int sx = ((nr ^ nc) & 7) << 4;
    const s16x4 v = *(const s16x4*)((const char*)(tmp + ((size_t)nr * 64 + nc) * 512)
                                    + ((2 * (pb * 64 + p4)) ^ sx));
#pragma unroll
    for (int j = 0; j < 4; ++j) tile[nc * 65 + p4 + j] = b2f(v[j]);
  }
  __syncthreads();
#pragma unroll
  for (int it = 0; it < 4; ++it) {
    const int idx = it * 256 + t;
    const int pi = idx >> 4, nc4 = (idx & 15) * 4;
    const int ch = 8 * pi + pb;
    float4 o;
#pragma unroll
    for (int j = 0; j < 4; ++j) (&o.x)[j] = tile[(nc4 + j) * 65 + pi];
    *(float4*)(out + (size_t)ch * 4096 + nr * 64 + nc4) = o;
  }
}

// Weights [3][512][512] f32 -> fragment order with k-elements in p-order.
__global__ void pack_w(const float* __restrict__ w0, const float* __restrict__ w1,
                       const float* __restrict__ w2, const float* __restrict__ w3,
                       const float* __restrict__ w4, const float* __restrict__ w5,
                       short* __restrict__ dst)
{
  const float* s;
  switch (blockIdx.y) {
    case 0: s = w0; break; case 1: s = w1; break; case 2: s = w2; break;
    case 3: s = w3; break; case 4: s = w4; break; default: s = w5; break;
  }
  const int idx = blockIdx.x * 256 + threadIdx.x;   // 0 .. 196607
  const int l = idx >> 16;
  const int r = idx & 65535;
  const int o = r >> 7, c4 = (r & 127) * 4;
  const float4 v = *(const float4*)(s + ((size_t)l * 512 + o) * 512 + c4);
  const int h = o & 7, row8 = o >> 3;
  const int mh = row8 >> 5, f = (row8 >> 4) & 1, l16r = row8 & 15;
  short* db = dst + (size_t)blockIdx.y * 786432 + (size_t)l * 262144;
#pragma unroll
  for (int j = 0; j < 4; ++j) {
    const int ch = c4 + j;
    const int p = ((ch & 7) << 6) | (ch >> 3);
    const int jj = p & 7, g4p = (p >> 3) & 3, kk = p >> 5;
    const int lane = g4p * 16 + l16r;
    db[(size_t)(((((h * 2 + mh) * 16 + kk) * 2 + f) * 64 + lane)) * 8 + jj] =
        f2b((&v.x)[j]);
  }
}

// Biases [3][512] f32 -> [name][l][h][64] f32
__global__ void pack_b(const float* __restrict__ b0, const float* __restrict__ b1,
                       const float* __restrict__ b2, const float* __restrict__ b3,
                       const float* __restrict__ b4, const float* __restrict__ b5,
                       float* __restrict__ dst)
{
  const int idx = blockIdx.x * 256 + threadIdx.x;   // 0..9215
  const int name = idx / 1536;
  const int rem  = idx - name * 1536;
  const int l = rem >> 9;
  const int p = rem & 511;
  const int h = p >> 6, d = p & 63;
  const float* s;
  switch (name) {
    case 0: s = b0; break; case 1: s = b1; break; case 2: s = b2; break;
    case 3: s = b3; break; case 4: s = b4; break; default: s = b5; break;
  }
  dst[idx] = s[l * 512 + 8 * d + h];
}

__global__ void copy_masks(const float* __restrict__ m, float* __restrict__ o) {
  const int i = blockIdx.x * 256 + threadIdx.x;
  ((float4*)o)[i] = ((const float4*)m)[i];
}

extern "C" void kernel_launch(void* const* d_in, const int* in_sizes, int n_in,
                              void* d_out, int out_size, void* d_ws, size_t ws_size,
                              hipStream_t stream)
{
  const float* x0    = (const float*)d_in[0];
  const float* masks = (const float*)d_in[1];
  short* wbf  = (short*)d_ws;                        // packed weights, 9.44 MB
  float* bws  = (float*)((char*)d_ws + 9437184);     // packed biases
  float* xbuf = (float*)d_out;
  float* mout = xbuf + 16777216;

  const size_t xw_off = 9474048;                     // after weights + biases
  const bool big = ws_size >= xw_off + (size_t)33554432;   // xw bf16 = 32 MB
  unsigned short* xw = big ? (unsigned short*)((char*)d_ws + xw_off)
                           : (unsigned short*)d_out;

  pack_w<<<dim3(768, 6), 256, 0, stream>>>(
      (const float*)d_in[2], (const float*)d_in[3], (const float*)d_in[4],
      (const float*)d_in[5], (const float*)d_in[6], (const float*)d_in[7], wbf);
  pack_b<<<36, 256, 0, stream>>>(
      (const float*)d_in[8], (const float*)d_in[9], (const float*)d_in[10],
      (const float*)d_in[11], (const float*)d_in[12], (const float*)d_in[13], bws);
  prep_x<<<512, 256, 64 * 521 * 4, stream>>>(x0, xw);
  copy_masks<<<32, 256, 0, stream>>>(masks, mout);

  const size_t WPL = 262144;
  for (int l = 0; l < 3; ++l) {
    attn_pass<0, 0><<<512, 1024, SM_TOTAL, stream>>>(
        xw, xbuf,
        wbf + (0 * 3 + l) * WPL, wbf + (1 * 3 + l) * WPL, wbf + (2 * 3 + l) * WPL,
        bws + (0 * 3 + l) * 512, bws + (1 * 3 + l) * 512, bws + (2 * 3 + l) * 512,
        masks);
    const short* rwk = wbf + (3 * 3 + l) * WPL;
    const short* rwq = wbf + (4 * 3 + l) * WPL;
    const short* rwv = wbf + (5 * 3 + l) * WPL;
    const float* rbk = bws + (3 * 3 + l) * 512;
    const float* rbq = bws + (4 * 3 + l) * 512;
    const float* rbv = bws + (5 * 3 + l) * 512;
    if (l == 2 && big)
      attn_pass<1, 1><<<512, 1024, SM_TOTAL, stream>>>(
          xw, xbuf, rwk, rwq, rwv, rbk, rbq, rbv, masks);
    else
      attn_pass<1, 0><<<512, 1024, SM_TOTAL, stream>>>(
          xw, xbuf, rwk, rwq, rwv, rbk, rbq, rbv, masks);
  }

  if (!big) {
    // xw (bf16, 32MB) aliases the front of d_out; un-permute per b-slab via a
    // ws bounce, in REVERSE order so out-writes never clobber unread slabs.
    for (int b = 7; b >= 0; --b) {
      hipMemcpyAsync(wbf, xw + (size_t)b * 2097152, 4194304,
                     hipMemcpyDeviceToDevice, stream);
      unperm_b<<<512, 256, 0, stream>>>((const unsigned short*)wbf,
                                        xbuf + (size_t)b * 2097152);
    }
  }
}